// Round 5
// baseline (159.339 us; speedup 1.0000x reference)
//
#include <hip/hip_runtime.h>
#include <math.h>

#define D 256              // feature dim: one row = 1 KB = one wave64 float4 load
#define NBLOCKS 1024
#define WAVES 4            // 256-thread blocks
#define NPW 16             // nodes per wave: 1024 blocks * 4 waves * 16 = 65536

// softplus(-p) = max(-p,0) + log(1+exp(-|p|)); fast intrinsics fine:
// threshold is 135 absolute on a ~6752 output (2%).
__device__ __forceinline__ float spn(float p) {
    return fmaxf(-p, 0.0f) + __logf(1.0f + __expf(-fabsf(p)));
}

__device__ __forceinline__ float dot4(float4 a, float4 b) {
    return a.x * b.x + a.y * b.y + a.z * b.z + a.w * b.w;
}

// Full 64-lane reduction, VALU-only (DPP). Result valid in lane 63.
__device__ __forceinline__ float wave64_reduce(float x) {
    int t;
    t = __builtin_amdgcn_update_dpp(0, __builtin_bit_cast(int, x), 0x111, 0xf, 0xf, true);
    x += __builtin_bit_cast(float, t);
    t = __builtin_amdgcn_update_dpp(0, __builtin_bit_cast(int, x), 0x112, 0xf, 0xf, true);
    x += __builtin_bit_cast(float, t);
    t = __builtin_amdgcn_update_dpp(0, __builtin_bit_cast(int, x), 0x114, 0xf, 0xf, true);
    x += __builtin_bit_cast(float, t);
    t = __builtin_amdgcn_update_dpp(0, __builtin_bit_cast(int, x), 0x118, 0xf, 0xf, true);
    x += __builtin_bit_cast(float, t);
    t = __builtin_amdgcn_update_dpp(0, __builtin_bit_cast(int, x), 0x142, 0xa, 0xf, true); // row_bcast15
    x += __builtin_bit_cast(float, t);
    t = __builtin_amdgcn_update_dpp(0, __builtin_bit_cast(int, x), 0x143, 0xc, 0xf, true); // row_bcast31
    x += __builtin_bit_cast(float, t);
    return x;   // lane 63 holds the full sum
}

// R0-R4 lesson: per-wave MLP was NOT the limiter (proven MLP=12 via
// global_load_lds changed nothing; 43-46us invariant across 4 structures).
// The invariant is TRAFFIC: 6 gathered rows/node = 384 MB of vector traffic,
// z-supply pinned at ~2.9 TB/s. Exploit sorted batch indices: a wave owns 16
// CONTIGUOUS nodes, caches its 4 g-rows in registers, reloads only when the
// wave-uniform index changes (~1x/wave). Traffic 384 -> ~150 MB; the loop is
// a pipelineable z-stream (the shape that reaches 6.3 TB/s in ubenches).
// Correctness never assumes sortedness: indices are compared every node.
__global__ __launch_bounds__(256) void jsd_dot_run_kernel(
    const int*   __restrict__ b1,
    const int*   __restrict__ b2,
    const float* __restrict__ z1,
    const float* __restrict__ z2,
    const float* __restrict__ g1,
    const float* __restrict__ g2,
    float*       __restrict__ partials)   // [NBLOCKS*2]
{
    const int wave = threadIdx.x >> 6;
    const int lane = threadIdx.x & 63;
    const int w    = blockIdx.x * WAVES + wave;

    // Wave-uniform first node -> scalar b-loads, SGPR z base.
    const int sbase = __builtin_amdgcn_readfirstlane(w * NPW);

    // All 32 indices up-front (uniform addresses -> s_load dwordx4 runs);
    // #pragma unroll keeps every access compile-time-indexed (rule #20).
    int i1v[NPW], i2v[NPW];
    #pragma unroll
    for (int j = 0; j < NPW; ++j) {
        i1v[j] = b1[sbase + j];
        i2v[j] = b2[sbase + j];
    }

    const float4* z1p = (const float4*)(z1 + (size_t)sbase * D);
    const float4* z2p = (const float4*)(z2 + (size_t)sbase * D);

    float acc1 = 0.0f, acc2 = 0.0f;

    // Register-cached g rows for the current run of equal indices.
    int ci1 = -1, ci2 = -1;
    float4 w11, w12, w22, w21;

    // Depth-2 software pipeline on the z stream: next node's rows are in
    // flight while the current node computes.
    float4 a1n = z1p[lane];
    float4 a2n = z2p[lane];

    #pragma unroll
    for (int j = 0; j < NPW; ++j) {
        const float4 a1 = a1n;
        const float4 a2 = a2n;
        if (j + 1 < NPW) {
            a1n = z1p[(j + 1) * (D / 4) + lane];
            a2n = z2p[(j + 1) * (D / 4) + lane];
        }

        const int i1 = i1v[j];
        const int i2 = i2v[j];
        // Wave-uniform compare -> scalar branch; taken ~once per wave on
        // sorted data, but correct for ANY index pattern.
        if (i1 != ci1) {
            w11 = ((const float4*)(g1 + (size_t)i1 * D))[lane];
            w12 = ((const float4*)(g2 + (size_t)i1 * D))[lane];
            ci1 = i1;
        }
        if (i2 != ci2) {
            w22 = ((const float4*)(g2 + (size_t)i2 * D))[lane];
            w21 = ((const float4*)(g1 + (size_t)i2 * D))[lane];
            ci2 = i2;
        }

        float s11 = wave64_reduce(dot4(a1, w11));
        float c12 = wave64_reduce(dot4(a1, w12));
        float s22 = wave64_reduce(dot4(a2, w22));
        float c21 = wave64_reduce(dot4(a2, w21));

        if (lane == 63) {
            float d1 = spn(c12) - spn(s11);   // f(s)-f(c) = softplus(-c)-softplus(-s)
            float d2 = spn(c21) - spn(s22);
            acc1 += d1 * d1;
            acc2 += d2 * d2;
        }
    }

    __shared__ float s1[WAVES], s2[WAVES];
    if (lane == 63) { s1[wave] = acc1; s2[wave] = acc2; }
    __syncthreads();

    if (threadIdx.x == 0) {
        float t1 = 0.0f, t2 = 0.0f;
        #pragma unroll
        for (int k = 0; k < WAVES; ++k) { t1 += s1[k]; t2 += s2[k]; }
        partials[blockIdx.x * 2 + 0] = t1;
        partials[blockIdx.x * 2 + 1] = t2;
    }
}

__global__ __launch_bounds__(256) void jsd_reduce_kernel(
    const float* __restrict__ partials,
    float*       __restrict__ out)
{
    const int tid  = threadIdx.x;
    const int wave = tid >> 6;
    const int lane = tid & 63;

    float a = 0.0f, b = 0.0f;
    #pragma unroll
    for (int i = 0; i < NBLOCKS / 256; ++i) {
        a += partials[(i * 256 + tid) * 2 + 0];
        b += partials[(i * 256 + tid) * 2 + 1];
    }

    a = wave64_reduce(a);
    b = wave64_reduce(b);

    __shared__ float s1[4], s2[4];
    if (lane == 63) { s1[wave] = a; s2[wave] = b; }
    __syncthreads();

    if (tid == 0) {
        float t1 = s1[0] + s1[1] + s1[2] + s1[3];
        float t2 = s2[0] + s2[1] + s2[2] + s2[3];
        out[0] = sqrtf(t1) + sqrtf(t2);
    }
}

extern "C" void kernel_launch(void* const* d_in, const int* in_sizes, int n_in,
                              void* d_out, int out_size, void* d_ws, size_t ws_size,
                              hipStream_t stream) {
    const int*   b1 = (const int*)  d_in[0];
    const int*   b2 = (const int*)  d_in[1];
    const float* z1 = (const float*)d_in[2];
    const float* z2 = (const float*)d_in[3];
    const float* g1 = (const float*)d_in[4];
    const float* g2 = (const float*)d_in[5];
    float* out      = (float*)d_out;
    float* partials = (float*)d_ws;   // NBLOCKS*2 floats, fully overwritten

    jsd_dot_run_kernel<<<NBLOCKS, 256, 0, stream>>>(b1, b2, z1, z2, g1, g2, partials);
    jsd_reduce_kernel<<<1, 256, 0, stream>>>(partials, out);
}

// Round 6
// 157.118 us; speedup vs baseline: 1.0141x; 1.0141x over previous
//
#include <hip/hip_runtime.h>
#include <math.h>

#define D 256              // feature dim
#define BLOCKS 2048
#define WPB 4              // waves per 256-thread block
#define GPW 4              // 2-node groups per wave: 2048*4*4*2 = 65536 nodes

// softplus(-p) = max(-p,0) + log(1+exp(-|p|)); fast intrinsics fine:
// threshold is 135 absolute on a ~6752 output (2%).
__device__ __forceinline__ float spn(float p) {
    return fmaxf(-p, 0.0f) + __logf(1.0f + __expf(-fabsf(p)));
}

__device__ __forceinline__ float dot4(float4 a, float4 b) {
    return a.x * b.x + a.y * b.y + a.z * b.z + a.w * b.w;
}

template<int CTRL, int ROWMASK>
__device__ __forceinline__ float dpp_add(float x) {
    int t = __builtin_amdgcn_update_dpp(0, __builtin_bit_cast(int, x), CTRL, ROWMASK, 0xf, true);
    return x + __builtin_bit_cast(float, t);
}

// 32-lane reduce: after this, lane 31 holds sum of lanes 0..31 and lane 63
// holds sum of lanes 32..63 (5 DPP adds; two independent halves).
__device__ __forceinline__ float red32(float x) {
    x = dpp_add<0x111, 0xf>(x);   // row_shr:1
    x = dpp_add<0x112, 0xf>(x);   // row_shr:2
    x = dpp_add<0x114, 0xf>(x);   // row_shr:4
    x = dpp_add<0x118, 0xf>(x);   // row_shr:8  -> lane 16r+15 = row sum
    x = dpp_add<0x142, 0xa>(x);   // row_bcast15: rows 1,3 += rows 0,2
    return x;
}

// Full 64-lane reduce (result in lane 63).
__device__ __forceinline__ float red64(float x) {
    x = red32(x);
    x = dpp_add<0x143, 0xc>(x);   // row_bcast31: upper half += lane31
    return x;
}

struct ZR { float4 a1lo, a1hi, a2lo, a2hi; };   // this lane's z slices (16 VGPR)

// R0-R5 lessons: (1) per-wave MLP was not the limiter (proven MLP=12 via
// global_load_lds: no change); (2) traffic was not the limiter (384->150 MB:
// no change). The invariant cost is the per-wave SERIAL chain: 4 x 6-step
// dependent DPP reduces + masked spn per node (~250 VALU instrs/node from
// VALUBusy arithmetic) with too few effectively-active waves. This version
// packs 2 nodes per wave-instruction (lane = 32*sub + fl, 8 floats/lane):
// reduction cost 24 -> 10 DPP/node in 4 independent chains, epilogue
// amortized x2, g-rows register-cached across the wave's contiguous 8-node
// strip (per-lane index compare: correct for ANY order, fast for sorted),
// depth-2 z prefetch, 8 waves/SIMD launched.
__global__ __launch_bounds__(256) void jsd_dot_gqr_kernel(
    const int*   __restrict__ b1,
    const int*   __restrict__ b2,
    const float* __restrict__ z1,
    const float* __restrict__ z2,
    const float* __restrict__ g1,
    const float* __restrict__ g2,
    float*       __restrict__ partials)   // [BLOCKS*2]
{
    const int wave = threadIdx.x >> 6;
    const int lane = threadIdx.x & 63;
    const int sub  = lane >> 5;          // which node of the 2-node group
    const int fl   = lane & 31;          // feature lane: floats [fl*8, fl*8+8)
    const bool tail = (fl == 31);        // lanes 31, 63 hold the node sums

    const int w    = blockIdx.x * WPB + wave;
    const int base = w * (GPW * 2);      // first node of this wave's strip

    const float* z1p = z1 + (size_t)(base + sub) * D + fl * 8;
    const float* z2p = z2 + (size_t)(base + sub) * D + fl * 8;

    ZR  zr[2];
    int i1v[2], i2v[2];

    // preload group 0
    zr[0].a1lo = ((const float4*)z1p)[0];
    zr[0].a1hi = ((const float4*)z1p)[1];
    zr[0].a2lo = ((const float4*)z2p)[0];
    zr[0].a2hi = ((const float4*)z2p)[1];
    i1v[0] = b1[base + sub];
    i2v[0] = b2[base + sub];

    // g-row register cache (per-lane 8 floats of each of the 4 rows).
    float4 w11lo{}, w11hi{}, w12lo{}, w12hi{};
    float4 w21lo{}, w21hi{}, w22lo{}, w22hi{};
    int ci1 = -1, ci2 = -1;

    float acc1 = 0.0f, acc2 = 0.0f;

    #pragma unroll
    for (int g = 0; g < GPW; ++g) {
        const int cur = g & 1;           // constant after unroll (rule #20)
        const int nxt = cur ^ 1;

        // prefetch next group's z slices + indices (in flight under compute)
        if (g + 1 < GPW) {
            const float* p1 = z1p + (size_t)(g + 1) * 2 * D;
            const float* p2 = z2p + (size_t)(g + 1) * 2 * D;
            zr[nxt].a1lo = ((const float4*)p1)[0];
            zr[nxt].a1hi = ((const float4*)p1)[1];
            zr[nxt].a2lo = ((const float4*)p2)[0];
            zr[nxt].a2hi = ((const float4*)p2)[1];
            i1v[nxt] = b1[base + (g + 1) * 2 + sub];
            i2v[nxt] = b2[base + (g + 1) * 2 + sub];
        }

        const int i1 = i1v[cur];
        const int i2 = i2v[cur];

        // Reload g rows only when some lane's index changed (wave-uniform
        // branch; ~3% of groups on sorted data, correct for any data).
        if (__any(i1 != ci1)) {
            const float* q = g1 + (size_t)i1 * D + fl * 8;
            const float* r = g2 + (size_t)i1 * D + fl * 8;
            w11lo = ((const float4*)q)[0]; w11hi = ((const float4*)q)[1];
            w12lo = ((const float4*)r)[0]; w12hi = ((const float4*)r)[1];
            ci1 = i1;
        }
        if (__any(i2 != ci2)) {
            const float* q = g2 + (size_t)i2 * D + fl * 8;
            const float* r = g1 + (size_t)i2 * D + fl * 8;
            w22lo = ((const float4*)q)[0]; w22hi = ((const float4*)q)[1];
            w21lo = ((const float4*)r)[0]; w21hi = ((const float4*)r)[1];
            ci2 = i2;
        }

        // 2 nodes per instruction: 16 FMA-class ops per node (invariant),
        // then 4 INDEPENDENT 5-step DPP chains (10 DPP/node vs 24 before).
        float p11 = dot4(zr[cur].a1lo, w11lo) + dot4(zr[cur].a1hi, w11hi);
        float p12 = dot4(zr[cur].a1lo, w12lo) + dot4(zr[cur].a1hi, w12hi);
        float p22 = dot4(zr[cur].a2lo, w22lo) + dot4(zr[cur].a2hi, w22hi);
        float p21 = dot4(zr[cur].a2lo, w21lo) + dot4(zr[cur].a2hi, w21hi);

        float s11 = red32(p11);
        float c12 = red32(p12);
        float s22 = red32(p22);
        float c21 = red32(p21);

        if (tail) {   // lanes 31,63: each finishes its own node
            float d1 = spn(c12) - spn(s11);   // f(s)-f(c) = softplus(-c)-softplus(-s)
            float d2 = spn(c21) - spn(s22);
            acc1 += d1 * d1;
            acc2 += d2 * d2;
        }
    }

    // acc lives on lanes 31,63 (0 elsewhere) -> full-wave sum to lane 63.
    acc1 = red64(acc1);
    acc2 = red64(acc2);

    __shared__ float s1[WPB], s2[WPB];
    if (lane == 63) { s1[wave] = acc1; s2[wave] = acc2; }
    __syncthreads();

    if (threadIdx.x == 0) {
        float t1 = 0.0f, t2 = 0.0f;
        #pragma unroll
        for (int k = 0; k < WPB; ++k) { t1 += s1[k]; t2 += s2[k]; }
        partials[blockIdx.x * 2 + 0] = t1;
        partials[blockIdx.x * 2 + 1] = t2;
    }
}

__global__ __launch_bounds__(256) void jsd_reduce_kernel(
    const float* __restrict__ partials,
    float*       __restrict__ out)
{
    const int tid  = threadIdx.x;
    const int wave = tid >> 6;
    const int lane = tid & 63;

    float a = 0.0f, b = 0.0f;
    #pragma unroll
    for (int i = 0; i < BLOCKS / 256; ++i) {
        a += partials[(i * 256 + tid) * 2 + 0];
        b += partials[(i * 256 + tid) * 2 + 1];
    }

    a = red64(a);
    b = red64(b);

    __shared__ float s1[4], s2[4];
    if (lane == 63) { s1[wave] = a; s2[wave] = b; }
    __syncthreads();

    if (tid == 0) {
        float t1 = s1[0] + s1[1] + s1[2] + s1[3];
        float t2 = s2[0] + s2[1] + s2[2] + s2[3];
        out[0] = sqrtf(t1) + sqrtf(t2);
    }
}

extern "C" void kernel_launch(void* const* d_in, const int* in_sizes, int n_in,
                              void* d_out, int out_size, void* d_ws, size_t ws_size,
                              hipStream_t stream) {
    const int*   b1 = (const int*)  d_in[0];
    const int*   b2 = (const int*)  d_in[1];
    const float* z1 = (const float*)d_in[2];
    const float* z2 = (const float*)d_in[3];
    const float* g1 = (const float*)d_in[4];
    const float* g2 = (const float*)d_in[5];
    float* out      = (float*)d_out;
    float* partials = (float*)d_ws;   // BLOCKS*2 floats, fully overwritten

    jsd_dot_gqr_kernel<<<BLOCKS, 256, 0, stream>>>(b1, b2, z1, z2, g1, g2, partials);
    jsd_reduce_kernel<<<1, 256, 0, stream>>>(partials, out);
}

// Round 7
// 156.531 us; speedup vs baseline: 1.0179x; 1.0038x over previous
//
#include <hip/hip_runtime.h>
#include <math.h>

#define D 256              // feature dim
#define BLOCKS 2048
#define WPB 4              // waves per 256-thread block
#define GPW 4              // 2-node groups per wave: 2048*4*4*2 = 65536 nodes

// Native vector type: __builtin_nontemporal_load requires scalar/vector,
// not HIP's struct float4.
using f32x4 = __attribute__((ext_vector_type(4))) float;

// softplus(-p) = max(-p,0) + log(1+exp(-|p|)); fast intrinsics fine:
// threshold is 135 absolute on a ~6752 output (2%).
__device__ __forceinline__ float spn(float p) {
    return fmaxf(-p, 0.0f) + __logf(1.0f + __expf(-fabsf(p)));
}

__device__ __forceinline__ float dot4(f32x4 a, f32x4 b) {
    return a.x * b.x + a.y * b.y + a.z * b.z + a.w * b.w;
}

// Non-temporal 16B load: z rows are touched exactly once per dispatch, so
// skip TCC allocation (and stop the 128MB z stream evicting the 1MB g set).
// R7's discriminator: if the ~3.1 TB/s read cap is TCC-allocation/track
// bound this moves it; if it's fabric-structural this is exactly neutral.
__device__ __forceinline__ f32x4 ntload(const f32x4* p) {
    return __builtin_nontemporal_load(p);
}

template<int CTRL, int ROWMASK>
__device__ __forceinline__ float dpp_add(float x) {
    int t = __builtin_amdgcn_update_dpp(0, __builtin_bit_cast(int, x), CTRL, ROWMASK, 0xf, true);
    return x + __builtin_bit_cast(float, t);
}

// 32-lane reduce: lane 31 holds sum of lanes 0..31, lane 63 of 32..63.
__device__ __forceinline__ float red32(float x) {
    x = dpp_add<0x111, 0xf>(x);   // row_shr:1
    x = dpp_add<0x112, 0xf>(x);   // row_shr:2
    x = dpp_add<0x114, 0xf>(x);   // row_shr:4
    x = dpp_add<0x118, 0xf>(x);   // row_shr:8
    x = dpp_add<0x142, 0xa>(x);   // row_bcast15
    return x;
}

// Full 64-lane reduce (result in lane 63).
__device__ __forceinline__ float red64(float x) {
    x = red32(x);
    x = dpp_add<0x143, 0xc>(x);   // row_bcast31
    return x;
}

struct ZR { f32x4 a1lo, a1hi, a2lo, a2hi; };   // this lane's z slices (16 VGPR)

// R0-R6: MLP (proven 12), traffic (384->150MB), occupancy (25-64%), and
// VALU chain (VALUBusy 30->16%) all falsified as limiters; effective read
// rate invariant at ~3.1 TB/s = the copy-ubench READ component, while
// write-only fill does 6.5 TB/s. This round isolates TCC allocation policy
// via non-temporal z loads; structure otherwise identical to R6.
__global__ __launch_bounds__(256) void jsd_dot_nt_kernel(
    const int*   __restrict__ b1,
    const int*   __restrict__ b2,
    const float* __restrict__ z1,
    const float* __restrict__ z2,
    const float* __restrict__ g1,
    const float* __restrict__ g2,
    float*       __restrict__ partials)   // [BLOCKS*2]
{
    const int wave = threadIdx.x >> 6;
    const int lane = threadIdx.x & 63;
    const int sub  = lane >> 5;          // which node of the 2-node group
    const int fl   = lane & 31;          // feature lane: floats [fl*8, fl*8+8)
    const bool tail = (fl == 31);        // lanes 31, 63 hold the node sums

    const int w    = blockIdx.x * WPB + wave;
    const int base = w * (GPW * 2);      // first node of this wave's strip

    const float* z1p = z1 + (size_t)(base + sub) * D + fl * 8;
    const float* z2p = z2 + (size_t)(base + sub) * D + fl * 8;

    ZR  zr[2];
    int i1v[2], i2v[2];

    // preload group 0 (non-temporal: zero-reuse stream)
    zr[0].a1lo = ntload((const f32x4*)z1p + 0);
    zr[0].a1hi = ntload((const f32x4*)z1p + 1);
    zr[0].a2lo = ntload((const f32x4*)z2p + 0);
    zr[0].a2hi = ntload((const f32x4*)z2p + 1);
    i1v[0] = b1[base + sub];
    i2v[0] = b2[base + sub];

    // g-row register cache (per-lane 8 floats of each of the 4 rows);
    // g loads stay NORMAL (cache-resident, reused across the strip).
    f32x4 w11lo{}, w11hi{}, w12lo{}, w12hi{};
    f32x4 w21lo{}, w21hi{}, w22lo{}, w22hi{};
    int ci1 = -1, ci2 = -1;

    float acc1 = 0.0f, acc2 = 0.0f;

    #pragma unroll
    for (int g = 0; g < GPW; ++g) {
        const int cur = g & 1;           // constant after unroll (rule #20)
        const int nxt = cur ^ 1;

        // prefetch next group's z slices + indices (in flight under compute)
        if (g + 1 < GPW) {
            const float* p1 = z1p + (size_t)(g + 1) * 2 * D;
            const float* p2 = z2p + (size_t)(g + 1) * 2 * D;
            zr[nxt].a1lo = ntload((const f32x4*)p1 + 0);
            zr[nxt].a1hi = ntload((const f32x4*)p1 + 1);
            zr[nxt].a2lo = ntload((const f32x4*)p2 + 0);
            zr[nxt].a2hi = ntload((const f32x4*)p2 + 1);
            i1v[nxt] = b1[base + (g + 1) * 2 + sub];
            i2v[nxt] = b2[base + (g + 1) * 2 + sub];
        }

        const int i1 = i1v[cur];
        const int i2 = i2v[cur];

        // Reload g rows only when some lane's index changed (wave-uniform
        // branch; rare on sorted data, correct for any data).
        if (__any(i1 != ci1)) {
            const float* q = g1 + (size_t)i1 * D + fl * 8;
            const float* r = g2 + (size_t)i1 * D + fl * 8;
            w11lo = ((const f32x4*)q)[0]; w11hi = ((const f32x4*)q)[1];
            w12lo = ((const f32x4*)r)[0]; w12hi = ((const f32x4*)r)[1];
            ci1 = i1;
        }
        if (__any(i2 != ci2)) {
            const float* q = g2 + (size_t)i2 * D + fl * 8;
            const float* r = g1 + (size_t)i2 * D + fl * 8;
            w22lo = ((const f32x4*)q)[0]; w22hi = ((const f32x4*)q)[1];
            w21lo = ((const f32x4*)r)[0]; w21hi = ((const f32x4*)r)[1];
            ci2 = i2;
        }

        // 2 nodes per wave-instruction; 4 independent 5-step DPP chains.
        float p11 = dot4(zr[cur].a1lo, w11lo) + dot4(zr[cur].a1hi, w11hi);
        float p12 = dot4(zr[cur].a1lo, w12lo) + dot4(zr[cur].a1hi, w12hi);
        float p22 = dot4(zr[cur].a2lo, w22lo) + dot4(zr[cur].a2hi, w22hi);
        float p21 = dot4(zr[cur].a2lo, w21lo) + dot4(zr[cur].a2hi, w21hi);

        float s11 = red32(p11);
        float c12 = red32(p12);
        float s22 = red32(p22);
        float c21 = red32(p21);

        if (tail) {   // lanes 31,63: each finishes its own node
            float d1 = spn(c12) - spn(s11);   // f(s)-f(c) = softplus(-c)-softplus(-s)
            float d2 = spn(c21) - spn(s22);
            acc1 += d1 * d1;
            acc2 += d2 * d2;
        }
    }

    // acc lives on lanes 31,63 (0 elsewhere) -> full-wave sum to lane 63.
    acc1 = red64(acc1);
    acc2 = red64(acc2);

    __shared__ float s1[WPB], s2[WPB];
    if (lane == 63) { s1[wave] = acc1; s2[wave] = acc2; }
    __syncthreads();

    if (threadIdx.x == 0) {
        float t1 = 0.0f, t2 = 0.0f;
        #pragma unroll
        for (int k = 0; k < WPB; ++k) { t1 += s1[k]; t2 += s2[k]; }
        partials[blockIdx.x * 2 + 0] = t1;
        partials[blockIdx.x * 2 + 1] = t2;
    }
}

__global__ __launch_bounds__(256) void jsd_reduce_kernel(
    const float* __restrict__ partials,
    float*       __restrict__ out)
{
    const int tid  = threadIdx.x;
    const int wave = tid >> 6;
    const int lane = tid & 63;

    float a = 0.0f, b = 0.0f;
    #pragma unroll
    for (int i = 0; i < BLOCKS / 256; ++i) {
        a += partials[(i * 256 + tid) * 2 + 0];
        b += partials[(i * 256 + tid) * 2 + 1];
    }

    a = red64(a);
    b = red64(b);

    __shared__ float s1[4], s2[4];
    if (lane == 63) { s1[wave] = a; s2[wave] = b; }
    __syncthreads();

    if (tid == 0) {
        float t1 = s1[0] + s1[1] + s1[2] + s1[3];
        float t2 = s2[0] + s2[1] + s2[2] + s2[3];
        out[0] = sqrtf(t1) + sqrtf(t2);
    }
}

extern "C" void kernel_launch(void* const* d_in, const int* in_sizes, int n_in,
                              void* d_out, int out_size, void* d_ws, size_t ws_size,
                              hipStream_t stream) {
    const int*   b1 = (const int*)  d_in[0];
    const int*   b2 = (const int*)  d_in[1];
    const float* z1 = (const float*)d_in[2];
    const float* z2 = (const float*)d_in[3];
    const float* g1 = (const float*)d_in[4];
    const float* g2 = (const float*)d_in[5];
    float* out      = (float*)d_out;
    float* partials = (float*)d_ws;   // BLOCKS*2 floats, fully overwritten

    jsd_dot_nt_kernel<<<BLOCKS, 256, 0, stream>>>(b1, b2, z1, z2, g1, g2, partials);
    jsd_reduce_kernel<<<1, 256, 0, stream>>>(partials, out);
}